// Round 14
// baseline (41.236 us; speedup 1.0000x reference)
//
#include <hip/hip_runtime.h>

typedef unsigned long long u64;

#define CC 32
#define NN 512
#define TT 12
#define NBLK 256     // one block per (batch, channel); == CU count
#define NTHR 256     // 2 n-elements per thread (proven shape)

__device__ __forceinline__ float eluf(float x){ return x>0.f ? x : (__expf(x)-1.f); }
__device__ __forceinline__ float elu3f(float x){ return eluf(eluf(eluf(x))); }
__device__ __forceinline__ float sigmf(float x){
  if (x>=0.f) return 1.f/(1.f+__expf(-x));
  float e=__expf(x); return e/(1.f+e);
}
__device__ __forceinline__ float tanhff(float x){
  return 1.f - 2.f/(__expf(2.f*x)+1.f);   // exact at saturation
}
__device__ __forceinline__ u64 pack_slot(unsigned tag, float v){
  return ((u64)tag<<32) | (u64)__float_as_uint(v);
}
__device__ __forceinline__ u64 ld_slot(u64* p){
  return __hip_atomic_load(p, __ATOMIC_RELAXED, __HIP_MEMORY_SCOPE_AGENT);
}
__device__ __forceinline__ void xch_slot(u64* p, u64 v){
  (void)__hip_atomic_exchange(p, v, __ATOMIC_RELAXED, __HIP_MEMORY_SCOPE_AGENT);
}

__global__ __launch_bounds__(NTHR, 1)
void glstm_fused(const float* __restrict__ xg,     // (B,C,N,T)
                 const float* __restrict__ cellg,  // (B,C,N)
                 const float* __restrict__ w1g,    // (T,8,C,C)
                 const float* __restrict__ w2g,    // (T,8,C,C)
                 const float* __restrict__ biasg,  // (4,C,N,T)
                 float* __restrict__ outg,         // (B,C,N,T) ++ (B,C,N)
                 u64* slots)
{
  // 96KB bias tile -> 1 block/CU (proven residency for the spin pipeline)
  __shared__ float biasL[4][TT][NN];
  __shared__ float preS[2][4];       // parity-buffered gate pre-activations
  __shared__ float wpart[TT][4];

  const int blk  = blockIdx.x;
  const int b    = blk >> 5;         // proven mapping (XCD-local mapping hurts)
  const int ch   = blk & 31;
  const int row  = blk;
  const int tid  = threadIdx.x;
  const int lane = tid & 63;
  const int wv   = tid >> 6;         // 0..3
  const int i0   = lane & 31;

  // csum: 4 per-wave partial slots per row, parity-buffered:
  //   cs4[par*NBLK*4 + row*4 + wv]; consumer sums 0,1,2,3 (fixed order ->
  //   bitwise identical to the old tid0 sum of the same 4 partials).
  u64* cs4     = slots;              // [2][NBLK][4]
  u64* xs_slot = slots + 2*NBLK*4;   // [TT][NBLK] tagged xsum, tag=1

  // ---- per-thread state: 2 n-elements ----
  const int n0 = 2*tid;
  float2 cc2 = *(const float2*)(cellg + row*NN + n0);
  float c0 = cc2.x, c1 = cc2.y;

  // ---- x rowsums per t + csum(state0) FIRST (publish gates the batch group) ----
  float xs[TT];
  #pragma unroll
  for (int t=0;t<TT;t++) xs[t]=0.f;
  const float* xrow = xg + row*NN*TT;
  #pragma unroll
  for (int half=0; half<2; half++){
    int n = tid + half*256;
    const float4* p = (const float4*)(xrow + n*TT);
    float4 v0=p[0], v1=p[1], v2=p[2];
    xs[0]+=v0.x;  xs[1]+=v0.y;  xs[2]+=v0.z;  xs[3]+=v0.w;
    xs[4]+=v1.x;  xs[5]+=v1.y;  xs[6]+=v1.z;  xs[7]+=v1.w;
    xs[8]+=v2.x;  xs[9]+=v2.y;  xs[10]+=v2.z; xs[11]+=v2.w;
  }
  float cp = c0 + c1;
  #pragma unroll
  for (int off=32; off>=1; off>>=1){
    #pragma unroll
    for (int t=0;t<TT;t++) xs[t] += __shfl_xor(xs[t], off, 64);
    cp += __shfl_xor(cp, off, 64);
  }
  if (lane == 0){
    #pragma unroll
    for (int t=0;t<TT;t++) wpart[t][wv] = xs[t];
    // publish own csum0 partial IMMEDIATELY (pre-barrier): earliest possible
    xch_slot(&cs4[row*4 + wv], pack_slot(1u, cp));
  }
  __syncthreads();
  if (tid < TT){
    float v = wpart[tid][0]+wpart[tid][1]+wpart[tid][2]+wpart[tid][3];
    xch_slot(&xs_slot[tid*NBLK + row], pack_slot(1u, v));
  }

  // ---- bias -> LDS (after publish; overlaps peers' publish latency) ----
  #pragma unroll
  for (int k=0;k<4;k++){
    #pragma unroll
    for (int half=0; half<2; half++){
      int n = tid + half*256;
      const float4* p = (const float4*)(biasg + ((k*CC + ch)*NN + n)*TT);
      float4 v0=p[0], v1=p[1], v2=p[2];
      biasL[k][0][n]=v0.x;  biasL[k][1][n]=v0.y;  biasL[k][2][n]=v0.z;  biasL[k][3][n]=v0.w;
      biasL[k][4][n]=v1.x;  biasL[k][5][n]=v1.y;  biasL[k][6][n]=v1.z;  biasL[k][7][n]=v1.w;
      biasL[k][8][n]=v2.x;  biasL[k][9][n]=v2.y;  biasL[k][10][n]=v2.z; biasL[k][11][n]=v2.w;
    }
  }

  // ---- head assignment + weight double-buffer (t=0 now) ----
  const int m = wv + ((lane >> 5) << 2);   // lanes<32: x-heads 0-3; lanes>=32: c-heads 4-7
  float w1p[2][32];
  float w2p[2];
  {
    const float* w1m = w1g + m*CC*CC + i0;
    #pragma unroll
    for (int j=0;j<32;j++) w1p[0][j] = w1m[j*CC];
    w2p[0] = w2g[(m*CC + i0)*CC + ch];
  }

  // ---- BATCHED gather of ALL peer xsums (r13-proven: one vmcnt window) ----
  float zxr[TT];
  {
    u64 vv[TT];
    int guard = 0;
    for (;;){
      #pragma unroll
      for (int t=0;t<TT;t++)
        vv[t] = ld_slot(&xs_slot[t*NBLK + b*CC + i0]);   // independent loads
      unsigned okm = 1u;
      #pragma unroll
      for (int t=0;t<TT;t++) okm &= (unsigned)((vv[t]>>32) == 1u);
      if (__all(okm)) break;
      __builtin_amdgcn_s_sleep(1);
      if (++guard > 200000) break;   // terminates instead of hanging
    }
    #pragma unroll
    for (int t=0;t<TT;t++) zxr[t] = __uint_as_float((unsigned)vv[t]);
  }

  // ---- 12 sequential steps, fully unrolled, ONE barrier per step ----
  float hm0[TT], hm1[TT];
  #pragma unroll
  for (int s=0;s<TT;s++){
    // hop: each lane polls its channel's 4 per-wave partials as independent
    // loads (one vmcnt window), sums in fixed order 0,1,2,3.
    float csv;
    {
      u64* pb = &cs4[((s&1)*NBLK + b*CC + i0)*4];
      const unsigned want = (unsigned)(s+1);
      u64 v0,v1,v2,v3;
      int guard = 0;
      for (;;){
        v0 = ld_slot(pb+0); v1 = ld_slot(pb+1);
        v2 = ld_slot(pb+2); v3 = ld_slot(pb+3);
        bool ok = ((unsigned)(v0>>32)==want) & ((unsigned)(v1>>32)==want)
                & ((unsigned)(v2>>32)==want) & ((unsigned)(v3>>32)==want);
        if (ok) break;
        __builtin_amdgcn_s_sleep(1);
        if (++guard > 1000000) break;   // terminates instead of hanging
      }
      csv = ((__uint_as_float((unsigned)v0) + __uint_as_float((unsigned)v1))
            + __uint_as_float((unsigned)v2)) + __uint_as_float((unsigned)v3);
    }
    float zs = (lane < 32) ? zxr[s] : csv;

    // head matvec from prefetched registers (no global loads post-poll)
    float pa = 0.f, pb2 = 0.f;
    #pragma unroll
    for (int j=0;j<16;j++){
      pa  = fmaf(__shfl(zs, j,    32), w1p[s&1][j],    pa);
      pb2 = fmaf(__shfl(zs, j+16, 32), w1p[s&1][j+16], pb2);
    }
    float s1 = pa + pb2;
    float h1 = eluf(eluf(s1));
    float pp = h1 * w2p[s&1];
    #pragma unroll
    for (int off=16; off>=1; off>>=1) pp += __shfl_xor(pp, off, 32);
    float ov = elu3f(512.f*pp);
    float prew = ov + __shfl_xor(ov, 32, 64);      // x-head + c-head
    if (lane == 0) preS[s&1][wv] = prew;

    // bias -> regs before the barrier (gate phase = pure VALU)
    float b00 = biasL[0][s][n0], b01 = biasL[0][s][n0+1];
    float b10 = biasL[1][s][n0], b11 = biasL[1][s][n0+1];
    float b20 = biasL[2][s][n0], b21 = biasL[2][s][n0+1];
    float b30 = biasL[3][s][n0], b31 = biasL[3][s][n0+1];

    __syncthreads();   // B1: preS[s&1] ready (the ONLY barrier per step;
                       // also separates preS parity reuse: read(s) < B1(s+1) < write(s+2))
    const float g0 = preS[s&1][0], g1 = preS[s&1][1];
    const float g2 = preS[s&1][2], g3 = preS[s&1][3];

    float ig0 = sigmf(g0 + b00);
    float fg0 = sigmf(g1 + b10);
    float ct0 = tanhff(g3 + b30);
    float ig1 = sigmf(g0 + b01);
    float fg1 = sigmf(g1 + b11);
    float ct1 = tanhff(g3 + b31);
    c0 = fg0*c0 + ig0*ct0;
    c1 = fg1*c1 + ig1*ct1;

    if (s < TT-1){
      const int par = (s+1)&1;
      // EARLY per-wave publish: no B2, no redS, no tid0 serialization.
      // Each wave's lane0 ships its partial the moment its reduce finishes.
      float csp = c0 + c1;
      #pragma unroll
      for (int off=32; off>=1; off>>=1) csp += __shfl_xor(csp, off, 64);
      if (lane == 0)
        xch_slot(&cs4[(par*NBLK + row)*4 + wv], pack_slot((unsigned)(s+2), csp));
      // prefetch next step's weights AFTER the publish point
      const float* w1m = w1g + ((s+1)*8 + m)*CC*CC + i0;
      #pragma unroll
      for (int j=0;j<32;j++) w1p[par][j] = w1m[j*CC];
      w2p[par] = w2g[(((s+1)*8 + m)*CC + i0)*CC + ch];
    }

    hm0[s] = sigmf(g2 + b20) * tanhff(c0);
    hm1[s] = sigmf(g2 + b21) * tanhff(c1);
  }

  // ---- coalesced epilogue: 2 n-rows x 12 t contiguous ----
  float4* op = (float4*)(outg + (row*NN + n0)*TT);
  op[0] = make_float4(hm0[0], hm0[1], hm0[2],  hm0[3]);
  op[1] = make_float4(hm0[4], hm0[5], hm0[6],  hm0[7]);
  op[2] = make_float4(hm0[8], hm0[9], hm0[10], hm0[11]);
  op[3] = make_float4(hm1[0], hm1[1], hm1[2],  hm1[3]);
  op[4] = make_float4(hm1[4], hm1[5], hm1[6],  hm1[7]);
  op[5] = make_float4(hm1[8], hm1[9], hm1[10], hm1[11]);
  *(float2*)(outg + NBLK*NN*TT + row*NN + n0) = make_float2(c0, c1);
}

extern "C" void kernel_launch(void* const* d_in, const int* in_sizes, int n_in,
                              void* d_out, int out_size, void* d_ws, size_t ws_size,
                              hipStream_t stream)
{
  (void)in_sizes; (void)n_in; (void)out_size; (void)ws_size;
  // setup_inputs order: input, cell, adj, w1, a1, w2, a2, bias
  const float* xg    = (const float*)d_in[0];
  const float* cellg = (const float*)d_in[1];
  const float* w1g   = (const float*)d_in[3];
  const float* w2g   = (const float*)d_in[5];
  const float* biasg = (const float*)d_in[7];
  float* outg = (float*)d_out;
  u64* slots = (u64*)d_ws;

  // reset sync tags every launch (ws is not re-poisoned between replays)
  hipMemsetAsync(d_ws, 0, (size_t)(2*NBLK*4 + TT*NBLK)*sizeof(u64), stream);
  glstm_fused<<<dim3(NBLK), dim3(NTHR), 0, stream>>>(xg, cellg, w1g, w2g, biasg, outg, slots);
}